// Round 7
// baseline (483.707 us; speedup 1.0000x reference)
//
#include <hip/hip_runtime.h>
#include <cstdint>

// TTLinear: y = x @ W^T + bias, W (4096x4096) reconstructed from TT cores,
// then a bf16 MFMA GEMM.
//
// R10: 32x32x16 MFMA with rotating fragment-register sets. R3-R9 all measure
// tile time ~= LDS-port cycles + matrix cycles (SUM, MfmaUtil 50-55%): with
// 16x16x32 fragments, reads for the next phase are WAR-dependent on the
// reused fragment regs, so in-order issue serializes port after pipe. At
// 32x32x16 a kstep (K=16) needs only 24 VGPR of fragments; TWO sets (S0/S1,
// 48 VGPR total, fits budget) rotate so each read batch is register-
// independent of the currently-issuing MFMA cluster: reads k2->S0 issue and
// drain through the LDS port WHILE the k1 cluster (S1) occupies the matrix
// pipe; counted lgkmcnt(6) gates each cluster. Staging: 8 global_load_lds
// per tile (2-deep buffer), one vmcnt(0)+barrier per tile boundary; loads
// issue >=2 ksteps (~1200cy) before the wait -> HBM latency covered.
// LDS: identity rows, 8x16B chunks/row, chunk c at slot c^(row&7) (proven
// R3/R9 swizzle; 32-row x 2-chunk reads are uniform 8-accesses/bank = min).
// Fragment layouts: A lane l: row=l&31, k=(l>>5)*8+i; B (from B^T rows):
// col-row=l&31, k=(l>>5)*8+i; D: row=(reg&3)+8*(reg>>2)+4*(l>>5), col=l&31
// (m74/m101-verified).
//
// ws layout: [0,64MiB) xb bf16, [64MiB,96MiB) Wbt bf16 (N x K), then C01 fp32.

typedef __bf16 bf16x8 __attribute__((ext_vector_type(8)));
typedef float f32x16 __attribute__((ext_vector_type(16)));
typedef unsigned short u16;
typedef u16 u16x8 __attribute__((ext_vector_type(8)));

__device__ __forceinline__ u16 f2bf(float f) {
    unsigned u = __builtin_bit_cast(unsigned, f);
    u += 0x7fffu + ((u >> 16) & 1u);   // round-to-nearest-even
    return (u16)(u >> 16);
}

// ---- kernel 1: x fp32 -> bf16 (8 elems/thread, 16B stores) ----
__global__ void k_cvt(const float* __restrict__ x, u16* __restrict__ xb) {
    long i = (long)blockIdx.x * blockDim.x + threadIdx.x;   // one per 8 floats
    const float4* p = (const float4*)x;
    float4 a = p[2 * i], b = p[2 * i + 1];
    u16x8 o;
    o[0] = f2bf(a.x); o[1] = f2bf(a.y); o[2] = f2bf(a.z); o[3] = f2bf(a.w);
    o[4] = f2bf(b.x); o[5] = f2bf(b.y); o[6] = f2bf(b.z); o[7] = f2bf(b.w);
    ((u16x8*)xb)[i] = o;
}

// ---- kernel 2: C01[o0][o1][i0][i1][b2] = sum_b1 core0[0,o0,i0,b1]*core1[b1,o1,i1,b2]
__global__ void k_c01(const float* __restrict__ c0, const float* __restrict__ c1,
                      float* __restrict__ c01) {
    int idx = blockIdx.x * 256 + threadIdx.x;   // 524288 total
    int b2 = idx & 7, i1 = (idx >> 3) & 15, i0 = (idx >> 7) & 15;
    int o1 = (idx >> 11) & 15, o0 = idx >> 15;
    float s = 0.f;
#pragma unroll
    for (int b1 = 0; b1 < 8; ++b1)
        s += c0[(o0 * 16 + i0) * 8 + b1] * c1[((b1 * 16 + o1) * 16 + i1) * 8 + b2];
    c01[idx] = s;
}

// ---- kernel 3: Wbt[o][i] bf16 (B^T layout, N x K); thread computes 8 consecutive i
__global__ void k_w(const float* __restrict__ c01, const float* __restrict__ c2,
                    u16* __restrict__ wbt) {
    int idx = blockIdx.x * 256 + threadIdx.x;   // 2,097,152 total
    int i2h = idx & 1;
    int i1 = (idx >> 1) & 15;
    int i0 = (idx >> 5) & 15;
    int o = idx >> 9;                            // 0..4095
    int o2 = o & 15, o1 = (o >> 4) & 15, o0 = o >> 8;
    const float* c = &c01[(((o0 * 16 + o1) * 16 + i0) * 16 + i1) * 8];
    float acc[8] = {0, 0, 0, 0, 0, 0, 0, 0};
#pragma unroll
    for (int b2 = 0; b2 < 8; ++b2) {
        float cv = c[b2];
        const float* cc = &c2[(b2 * 16 + o2) * 16 + i2h * 8];
#pragma unroll
        for (int j = 0; j < 8; ++j) acc[j] += cv * cc[j];
    }
    u16x8 ov;
#pragma unroll
    for (int j = 0; j < 8; ++j) ov[j] = f2bf(acc[j]);
    ((u16x8*)wbt)[(long)o * 512 + (i0 * 32 + i1 * 2 + i2h)] = ov;
}

// ---- kernel 4: GEMM. C[m][n] = sum_k A[m,k]*B[n,k] + bias[n] ----
#define BM 256
#define BN 256
#define BK 64
// LDS byte map: A0 @ 0, A1 @ 32768, B0 @ 65536, B1 @ 98304 (32 KiB each)
#define LDS_BYTES 131072

__device__ __forceinline__ void gload_lds16(const void* g, void* l) {
    __builtin_amdgcn_global_load_lds(
        (const __attribute__((address_space(1))) unsigned*)g,
        (__attribute__((address_space(3))) unsigned*)l, 16, 0, 0);
}

#define VMW(N)  asm volatile("s_waitcnt vmcnt(" #N ")" ::: "memory")
#define LGKM(N) asm volatile("s_waitcnt lgkmcnt(" #N ")" ::: "memory")
#define BAR()   __builtin_amdgcn_s_barrier()
#define SCHED0  __builtin_amdgcn_sched_barrier(0)

// 6 ds_read_b128 for kstep KS from buffer BUF into sets AF[4], BF[2].
// A byte addr = vA[KS] (incl wm*16384 + row*128 + swizzled chunk*16)
//             + imm(BUF*32768 + mi*4096).
// B byte addr = vB[KS] (incl 65536 + wn*8192 + row*128 + chunk*16)
//             + imm(BUF*32768 + ni*4096).
#define READ6(KS, AF, BF, BUF) do { \
    _Pragma("unroll") for (int mi_ = 0; mi_ < 4; ++mi_) \
        AF[mi_] = *(const bf16x8*)(ldsb + vA[KS] + ((BUF) * 32768 + mi_ * 4096)); \
    _Pragma("unroll") for (int ni_ = 0; ni_ < 2; ++ni_) \
        BF[ni_] = *(const bf16x8*)(ldsb + vB[KS] + ((BUF) * 32768 + ni_ * 4096)); \
} while (0)

// one kstep: 8 MFMA 32x32x16 (4 M-tiles x 2 N-tiles), acc += A*B
#define MFMA8(AF, BF) do { \
    __builtin_amdgcn_s_setprio(1); \
    _Pragma("unroll") for (int mi_ = 0; mi_ < 4; ++mi_) \
    _Pragma("unroll") for (int ni_ = 0; ni_ < 2; ++ni_) \
        acc[mi_][ni_] = __builtin_amdgcn_mfma_f32_32x32x16_bf16( \
            AF[mi_], BF[ni_], acc[mi_][ni_], 0, 0, 0); \
    __builtin_amdgcn_s_setprio(0); \
} while (0)

// stage quarter-tile G (512 x 16B chunks) of tile at k-offset KO into DSTBUF
#define GLOADA(G, DSTBUF, KO) \
    gload_lds16(paT + (long)(G) * 64 * 4096 + (KO), \
                ldsw + (DSTBUF) * 32768 + (G) * 8192 + t * 16)
#define GLOADB(G, DSTBUF, KO) \
    gload_lds16(pbT + (long)(G) * 64 * 4096 + (KO), \
                ldsw + 65536 + (DSTBUF) * 32768 + (G) * 8192 + t * 16)

// One K-tile (4 ksteps). Reads buf BUF; stages tile TT+1 into 1-BUF when PRE.
// lgkm ledger (in-order ds completion): after READ6 x2 -> 12 out; LGKM(6)
// => k0 set done. +6 (k2) -> LGKM(6) => first 12 done (k1 ready). +6 (k3)
// -> LGKM(6) => first 18 done (k2 ready). LGKM(0) => k3 ready. Each read
// batch drains through the LDS port while the previous cluster occupies the
// matrix pipe (register-independent sets -> no WAR serialization).
#define TILE(BUF, TT, PRE) do { \
    const long ko_ = (long)((TT) + 1) * BK; \
    READ6(0, a0, b0, BUF); \
    READ6(1, a1, b1, BUF); \
    LGKM(6); SCHED0; \
    MFMA8(a0, b0); \
    if (PRE) { GLOADA(0, 1 - (BUF), ko_); GLOADA(1, 1 - (BUF), ko_); \
               GLOADA(2, 1 - (BUF), ko_); GLOADA(3, 1 - (BUF), ko_); } \
    READ6(2, a0, b0, BUF); \
    LGKM(6); SCHED0; \
    MFMA8(a1, b1); \
    if (PRE) { GLOADB(0, 1 - (BUF), ko_); GLOADB(1, 1 - (BUF), ko_); \
               GLOADB(2, 1 - (BUF), ko_); GLOADB(3, 1 - (BUF), ko_); } \
    READ6(3, a1, b1, BUF); \
    LGKM(6); SCHED0; \
    MFMA8(a0, b0); \
    LGKM(0); SCHED0; \
    MFMA8(a1, b1); \
    VMW(0); BAR(); \
} while (0)

__launch_bounds__(512, 2)
__global__ void k_gemm(const u16* __restrict__ A, const u16* __restrict__ B,
                       const float* __restrict__ bias, float* __restrict__ C,
                       int M, int N, int K) {
    extern __shared__ __align__(16) u16 lds[];
    char* ldsw = (char*)lds;
    const char* ldsb = (const char*)lds;

    // XCD-aware swizzle: 512 blocks, 8 XCDs, 64 blocks/chunk (bijective).
    const int wg = blockIdx.x;
    const int swzb = (wg & 7) * 64 + (wg >> 3);
    const int bn = swzb & 15, bm = swzb >> 4;     // 16 N-blocks x 32 M-blocks
    const int m0 = bm * BM, n0 = bn * BN;

    const int t = threadIdx.x;
    const int wave = t >> 6, lane = t & 63;
    const int wm = wave >> 2, wn = wave & 3;      // 2 (M) x 4 (N) waves
    const int l31 = lane & 31, hi = lane >> 5, l7 = lane & 7;

    // Staging source (identity rows): thread t covers LDS chunk t of each
    // 512-chunk quarter; row = t>>3 (+G*64), slot t&7 holds global chunk
    // c = (t&7)^((t>>3)&7). Per-wave: 8 rows x 128B contiguous (R3-proven).
    const int srow = t >> 3;
    const int sc = (t & 7) ^ (srow & 7);
    const u16* paT = A + (long)m0 * K + (long)srow * K + sc * 8;
    const u16* pbT = B + (long)n0 * K + (long)srow * K + sc * 8;

    // Fragment-read byte addrs per kstep: row l31 (stride 128B), chunk
    // (2ks+hi) at swizzled slot (2ks+hi)^l7.
    int vA[4], vB[4];
#pragma unroll
    for (int ks = 0; ks < 4; ++ks) {
        int so = ((2 * ks + hi) ^ l7) << 4;
        vA[ks] = wm * 16384 + l31 * 128 + so;
        vB[ks] = 65536 + wn * 8192 + l31 * 128 + so;
    }

    f32x16 acc[4][2];
#pragma unroll
    for (int mi = 0; mi < 4; ++mi)
#pragma unroll
        for (int ni = 0; ni < 2; ++ni) acc[mi][ni] = 0.f;

    bf16x8 a0[4], a1[4], b0[2], b1[2];

    // Prologue: stage tile 0 into buf0, drain, sync.
    GLOADA(0, 0, 0); GLOADA(1, 0, 0); GLOADA(2, 0, 0); GLOADA(3, 0, 0);
    GLOADB(0, 0, 0); GLOADB(1, 0, 0); GLOADB(2, 0, 0); GLOADB(3, 0, 0);
    VMW(0); BAR();

    // K = 4096 -> 64 tiles: 31 unrolled pairs + tile 62 (PRE) + 63 (tail).
#pragma unroll 1
    for (int tt = 0; tt < 62; tt += 2) {
        TILE(0, tt,     1);
        TILE(1, tt + 1, 1);
    }
    TILE(0, 62, 1);
    TILE(1, 63, 0);

    // Epilogue: D row=(reg&3)+8*(reg>>2)+4*hi, col=l31; add bias, store fp32.
#pragma unroll
    for (int ni = 0; ni < 2; ++ni) {
        int gn = n0 + wn * 64 + ni * 32 + l31;
        float bv = bias[gn];
#pragma unroll
        for (int mi = 0; mi < 4; ++mi) {
            int gm = m0 + wm * 128 + mi * 32 + 4 * hi;
#pragma unroll
            for (int reg = 0; reg < 16; ++reg) {
                int r = (reg & 3) + 8 * (reg >> 2);
                C[(long)(gm + r) * N + gn] = acc[mi][ni][reg] + bv;
            }
        }
    }
}

extern "C" void kernel_launch(void* const* d_in, const int* in_sizes, int n_in,
                              void* d_out, int out_size, void* d_ws, size_t ws_size,
                              hipStream_t stream) {
    const float* x = (const float*)d_in[0];
    const float* c0 = (const float*)d_in[1];
    const float* c1 = (const float*)d_in[2];
    const float* c2 = (const float*)d_in[3];
    const float* bias = (const float*)d_in[4];
    float* out = (float*)d_out;

    const int Mb = 8192, Nf = 4096, Kf = 4096;
    char* ws = (char*)d_ws;
    u16* xb = (u16*)ws;                                       // 67,108,864 B
    u16* wbt = (u16*)(ws + 67108864);                         // 33,554,432 B
    float* c01 = (float*)(ws + 67108864 + 33554432);          //  2,097,152 B

    // 128 KiB dynamic LDS (> 64 KiB static limit). Idempotent, capture-safe.
    hipFuncSetAttribute(reinterpret_cast<const void*>(k_gemm),
                        hipFuncAttributeMaxDynamicSharedMemorySize, LDS_BYTES);

    k_cvt<<<dim3((Mb * Kf / 8) / 256), 256, 0, stream>>>(x, xb);
    k_c01<<<dim3(2048), 256, 0, stream>>>(c0, c1, c01);
    k_w<<<dim3(8192), 256, 0, stream>>>(c01, c2, wbt);
    k_gemm<<<dim3((Mb / BM) * (Nf / BN)), dim3(512), LDS_BYTES, stream>>>(
        xb, wbt, bias, out, Mb, Nf, Kf);
}

// Round 8
// 470.564 us; speedup vs baseline: 1.0279x; 1.0279x over previous
//
#include <hip/hip_runtime.h>
#include <cstdint>

// TTLinear: y = x @ W^T + bias, W (4096x4096) reconstructed from TT cores,
// then a bf16 MFMA GEMM.
//
// R11: prologue collapse. Across R0-R10, dur_us - k_gemm is a constant
// ~225 us (48% of wall clock) while the three prologue kernels' roofline
// cost is ~55 us. R11 fuses them into ONE kernel (2 launches total):
//  - k_c01 is inlined into the W-builder: each thread recomputes its 8
//    c01 values from the L1/L2-resident c0 (2KB) / c1 (64KB) tables with
//    the same b1-ascending order -> bit-identical W, c01 kernel+workspace
//    eliminated.
//  - cvt and W-build run as one dual-role kernel (blockIdx<2048 -> cvt,
//    8-iter stride; else W, 4-iter stride; independent outputs).
// k_gemm is R9 verbatim (best measured: 237 us, MfmaUtil 52%, 0 bank
// conflicts, absmax exact), so any total change is pure prologue effect.
//
// ws layout: [0,64MiB) xb bf16, [64MiB,96MiB) Wbt bf16 (N x K).

typedef __bf16 bf16x8 __attribute__((ext_vector_type(8)));
typedef float f32x4 __attribute__((ext_vector_type(4)));
typedef unsigned short u16;
typedef u16 u16x8 __attribute__((ext_vector_type(8)));

__device__ __forceinline__ u16 f2bf(float f) {
    unsigned u = __builtin_bit_cast(unsigned, f);
    u += 0x7fffu + ((u >> 16) & 1u);   // round-to-nearest-even
    return (u16)(u >> 16);
}

// ---- fused prologue: blocks [0,2048) convert x -> bf16 (8 iters);
// ---- blocks [2048,4096) build Wbt with c01 inlined (4 iters).
__global__ void k_pre(const float* __restrict__ x, u16* __restrict__ xb,
                      const float* __restrict__ c0, const float* __restrict__ c1,
                      const float* __restrict__ c2, u16* __restrict__ wbt) {
    const int b = blockIdx.x;
    if (b < 2048) {
        // x fp32 -> bf16: 33,554,432 floats = 4,194,304 u16x8 units.
        // 2048 blocks x 256 thr x 8 iters, contiguous sweep per iter.
        const float4* p = (const float4*)x;
        long base = (long)b * 256 + threadIdx.x;
#pragma unroll
        for (int it = 0; it < 8; ++it) {
            long i = base + (long)it * 524288;
            float4 a = p[2 * i], v = p[2 * i + 1];
            u16x8 o;
            o[0] = f2bf(a.x); o[1] = f2bf(a.y); o[2] = f2bf(a.z); o[3] = f2bf(a.w);
            o[4] = f2bf(v.x); o[5] = f2bf(v.y); o[6] = f2bf(v.z); o[7] = f2bf(v.w);
            ((u16x8*)xb)[i] = o;
        }
    } else {
        // Wbt[o][i] bf16 (N x K layout); thread computes 8 consecutive i.
        // 2,097,152 total items: 2048 blocks x 256 thr x 4 iters.
        int tb = (b - 2048) * 256 + threadIdx.x;
#pragma unroll 1
        for (int it = 0; it < 4; ++it) {
            int idx = tb + it * 524288;
            int i2h = idx & 1;
            int i1 = (idx >> 1) & 15;
            int i0 = (idx >> 5) & 15;
            int o = idx >> 9;                    // 0..4095
            int o2 = o & 15, o1 = (o >> 4) & 15, o0 = o >> 8;
            // inline c01: cb[b2] = sum_b1 c0[o0,i0,b1] * c1[b1,o1,i1,b2]
            // (b1 ascending, fp32 -> bit-identical to the old k_c01)
            float cb[8] = {0, 0, 0, 0, 0, 0, 0, 0};
#pragma unroll
            for (int b1 = 0; b1 < 8; ++b1) {
                float c0v = c0[(o0 * 16 + i0) * 8 + b1];
                const float* c1r = &c1[((b1 * 16 + o1) * 16 + i1) * 8];
#pragma unroll
                for (int b2 = 0; b2 < 8; ++b2) cb[b2] += c0v * c1r[b2];
            }
            float acc[8] = {0, 0, 0, 0, 0, 0, 0, 0};
#pragma unroll
            for (int b2 = 0; b2 < 8; ++b2) {
                float cv = cb[b2];
                const float* cc = &c2[(b2 * 16 + o2) * 16 + i2h * 8];
#pragma unroll
                for (int j = 0; j < 8; ++j) acc[j] += cv * cc[j];
            }
            u16x8 ov;
#pragma unroll
            for (int j = 0; j < 8; ++j) ov[j] = f2bf(acc[j]);
            ((u16x8*)wbt)[(long)o * 512 + (i0 * 32 + i1 * 2 + i2h)] = ov;
        }
    }
}

// ---- GEMM (R9 verbatim). C[m][n] = sum_k A[m,k]*B[n,k] + bias[n] ----
#define BM 256
#define BN 256
#define BK 64
#define TILEU (BM * BK)                 // 16384 u16 = 32 KiB per operand buf
#define LDS_BYTES (4 * TILEU * 2)       // 2 bufs x (A+B) x 2B = 131072

static_assert(LDS_BYTES == 131072, "lds size");

__device__ __forceinline__ void gload_lds16(const void* g, void* l) {
    __builtin_amdgcn_global_load_lds(
        (const __attribute__((address_space(1))) unsigned*)g,
        (__attribute__((address_space(3))) unsigned*)l, 16, 0, 0);
}

#define VMW(N) asm volatile("s_waitcnt vmcnt(" #N ")" ::: "memory")
#define LGKM0  asm volatile("s_waitcnt lgkmcnt(0)" ::: "memory")
#define BAR()  __builtin_amdgcn_s_barrier()
#define SCHED0 __builtin_amdgcn_sched_barrier(0)

// read A phase-half H (8 x ds_read_b128) from BASE into DST[8]
#define READ_A(H, DST, BASE) do { \
    _Pragma("unroll") for (int mi_ = 0; mi_ < 4; ++mi_) { \
        DST[mi_ * 2 + 0] = *(const bf16x8*)&(BASE)[arow + ((H) * 128 + mi_ * 16) * 64 + swz0]; \
        DST[mi_ * 2 + 1] = *(const bf16x8*)&(BASE)[arow + ((H) * 128 + mi_ * 16) * 64 + swz1]; \
    } } while (0)

// read B phase-half G (4 x ds_read_b128) from BASE into DST[4]
#define READ_B(G, DST, BASE) do { \
    _Pragma("unroll") for (int ni_ = 0; ni_ < 2; ++ni_) { \
        DST[ni_ * 2 + 0] = *(const bf16x8*)&(BASE)[brow + ((G) * 128 + ni_ * 16) * 64 + swz0]; \
        DST[ni_ * 2 + 1] = *(const bf16x8*)&(BASE)[brow + ((G) * 128 + ni_ * 16) * 64 + swz1]; \
    } } while (0)

// one C-quadrant: 16 MFMA (4 Mfrag x 2 Nfrag x 2 kk), kk ascending = K order
#define MFMA16(ASET, BF, H, G) do { \
    __builtin_amdgcn_s_setprio(1); \
    _Pragma("unroll") for (int mi_ = 0; mi_ < 4; ++mi_) \
    _Pragma("unroll") for (int ni_ = 0; ni_ < 2; ++ni_) \
    _Pragma("unroll") for (int kk_ = 0; kk_ < 2; ++kk_) \
        acc[(H) * 4 + mi_][(G) * 2 + ni_] = __builtin_amdgcn_mfma_f32_16x16x32_bf16( \
            ASET[mi_ * 2 + kk_], BF[ni_ * 2 + kk_], acc[(H) * 4 + mi_][(G) * 2 + ni_], 0, 0, 0); \
    __builtin_amdgcn_s_setprio(0); \
} while (0)

// One K-tile. Reads buf BUF; stages tile TT+1 into buf 1-BUF (when PRE).
// Quadrants Q1..Q4 = (M0N0),(M0N1),(M1N0),(M1N1); lifetimes nest (A0 dies
// after Q2 -> A1 reuses aA; b0 dies after Q3). Each ds_read batch issues
// right after the MFMA cluster that last reads its dest regs. VM invariant
// (steady): entering P1 outstanding {B1',A1'}=4; P1 stages A0',B0' (->8),
// VMW(4) retires B1',A1'; P2 stages B1',A1' (->8); P3-top VMW(4) retires
// A0',B0' (read by the prefetch reads after BAR#2).
#define TILE(BUF, TT, PRE) do { \
    const u16* aT = lds + (BUF) * TILEU; \
    const u16* bT = lds + 2 * TILEU + (BUF) * TILEU; \
    u16* sA = lds + (1 - (BUF)) * TILEU; \
    u16* sB = lds + 2 * TILEU + (1 - (BUF)) * TILEU; \
    const long ko = (long)((TT) + 1) * BK; \
    /* P1: stage A0',B0' | Q1 = A0 x B0 | retire B1',A1' | issue B1 reads */ \
    if (PRE) { gload_lds16(pa[0] + ko, sA + t * 8); \
               gload_lds16(pa[1] + ko, sA + 4096 + t * 8); \
               gload_lds16(pb[0] + ko, sB + t * 8); \
               gload_lds16(pb[1] + ko, sB + 4096 + t * 8); } \
    LGKM0; SCHED0; \
    MFMA16(aA, b0, 0, 0); \
    if (PRE) { VMW(4); } else { VMW(0); } \
    BAR(); \
    READ_B(1, b1, bT); \
    /* P2: stage B1',A1' | Q2 = A0 x B1 | issue A1 reads (aA WAR after Q2) */ \
    if (PRE) { gload_lds16(pb[2] + ko, sB + 8192 + t * 8); \
               gload_lds16(pb[3] + ko, sB + 12288 + t * 8); \
               gload_lds16(pa[2] + ko, sA + 8192 + t * 8); \
               gload_lds16(pa[3] + ko, sA + 12288 + t * 8); } \
    LGKM0; SCHED0; \
    MFMA16(aA, b1, 0, 1); \
    READ_A(1, aA, aT); \
    /* P3: retire A0',B0'; BAR#2 | Q3 = A1 x B0 | issue B0' prefetch reads */ \
    if (PRE) { VMW(4); BAR(); } \
    LGKM0; SCHED0; \
    MFMA16(aA, b0, 1, 0); \
    if (PRE) { READ_B(0, b0, sB); } \
    /* P4: Q4 = A1 x B1 | issue A0' prefetch reads (next tile's A0) */ \
    MFMA16(aA, b1, 1, 1); \
    if (PRE) { READ_A(0, aA, sA); } \
} while (0)

__launch_bounds__(512, 2)
__global__ void k_gemm(const u16* __restrict__ A, const u16* __restrict__ B,
                       const float* __restrict__ bias, float* __restrict__ C,
                       int M, int N, int K) {
    extern __shared__ __align__(16) u16 lds[];

    // XCD-aware swizzle: 512 blocks, 8 XCDs, 64 blocks/chunk (bijective).
    const int wg = blockIdx.x;
    const int swzb = (wg & 7) * 64 + (wg >> 3);
    const int bn = swzb & 15, bm = swzb >> 4;     // 16 N-blocks x 32 M-blocks
    const int m0 = bm * BM, n0 = bn * BN;

    const int t = threadIdx.x;
    const int wave = t >> 6, lane = t & 63;
    const int wm = wave >> 2, wn = wave & 3;      // 2 (M) x 4 (N) waves
    const int lr = lane & 15, quad = lane >> 4;

    // Staging with phase-permuted row layout (verified R7/R9). Thread loads
    // chunks ci = j*512+t (j=0..3); LDS linear in ci. LDS row lrow = ci>>3:
    //   A: rA = ((lrow>>6)&1)*128 + (lrow>>7)*64 + (lrow&63)
    //   B: rB = ((lrow>>5)&3)*64 + (lrow>>7)*32 + (lrow&31)
    // Chunk swizzle: lds slot (ci&7) holds global chunk (ci&7)^(lrow&7).
    const u16 *pa[4], *pb[4];
#pragma unroll
    for (int j = 0; j < 4; ++j) {
        int ci = j * 512 + t;
        int lrow = ci >> 3;
        int c = (ci & 7) ^ (lrow & 7);
        int rA = ((lrow >> 6) & 1) * 128 + (lrow >> 7) * 64 + (lrow & 63);
        int rB = ((lrow >> 5) & 3) * 64 + (lrow >> 7) * 32 + (lrow & 31);
        pa[j] = &A[(long)(m0 + rA) * K + c * 8];
        pb[j] = &B[(long)(n0 + rB) * K + c * 8];
    }

    // Fragment-read constants (verified: 0 bank conflicts).
    const int swz0 = ((quad    ) ^ (lr & 7)) * 8;
    const int swz1 = ((quad + 4) ^ (lr & 7)) * 8;
    const int arow = (wm * 64 + lr) * 64;         // + H*128*64 in READ_A
    const int brow = (wn * 32 + lr) * 64;         // + G*128*64 in READ_B

    f32x4 acc[8][4];
#pragma unroll
    for (int mi = 0; mi < 8; ++mi)
#pragma unroll
        for (int ni = 0; ni < 4; ++ni) acc[mi][ni] = 0.f;

    bf16x8 aA[8], b0[4], b1[4];

    // Prologue: stage tile 0 -> buf0 (order A0,B0,B1,A1), drain once,
    // then issue tile-0 A0/B0 fragment reads (waited by t0-P1's lgkm0).
    gload_lds16(pa[0], lds + t * 8);
    gload_lds16(pa[1], lds + 4096 + t * 8);
    gload_lds16(pb[0], lds + 2 * TILEU + t * 8);
    gload_lds16(pb[1], lds + 2 * TILEU + 4096 + t * 8);
    gload_lds16(pb[2], lds + 2 * TILEU + 8192 + t * 8);
    gload_lds16(pb[3], lds + 2 * TILEU + 12288 + t * 8);
    gload_lds16(pa[2], lds + 8192 + t * 8);
    gload_lds16(pa[3], lds + 12288 + t * 8);
    VMW(0); BAR();
    READ_A(0, aA, lds);
    READ_B(0, b0, (lds + 2 * TILEU));

    // K = 4096 -> 64 tiles: 31 unrolled pairs + tiles 62 (PRE) and 63 (tail).
#pragma unroll 1
    for (int tt = 0; tt < 62; tt += 2) {
        TILE(0, tt,     1);
        TILE(1, tt + 1, 1);
    }
    TILE(0, 62, 1);
    TILE(1, 63, 0);

    // Epilogue: D row = quad*4 + r (m), col = lr (n); add bias, store fp32.
#pragma unroll
    for (int ni = 0; ni < 4; ++ni) {
        int gn = n0 + wn * 64 + ni * 16 + lr;
        float bv = bias[gn];
#pragma unroll
        for (int mi = 0; mi < 8; ++mi) {
            int gm = m0 + wm * 128 + mi * 16 + quad * 4;
#pragma unroll
            for (int r = 0; r < 4; ++r)
                C[(long)(gm + r) * N + gn] = acc[mi][ni][r] + bv;
        }
    }
}

extern "C" void kernel_launch(void* const* d_in, const int* in_sizes, int n_in,
                              void* d_out, int out_size, void* d_ws, size_t ws_size,
                              hipStream_t stream) {
    const float* x = (const float*)d_in[0];
    const float* c0 = (const float*)d_in[1];
    const float* c1 = (const float*)d_in[2];
    const float* c2 = (const float*)d_in[3];
    const float* bias = (const float*)d_in[4];
    float* out = (float*)d_out;

    const int Mb = 8192, Nf = 4096, Kf = 4096;
    char* ws = (char*)d_ws;
    u16* xb = (u16*)ws;                                       // 67,108,864 B
    u16* wbt = (u16*)(ws + 67108864);                         // 33,554,432 B

    // 128 KiB dynamic LDS (> 64 KiB static limit). Idempotent, capture-safe.
    hipFuncSetAttribute(reinterpret_cast<const void*>(k_gemm),
                        hipFuncAttributeMaxDynamicSharedMemorySize, LDS_BYTES);

    k_pre<<<dim3(4096), 256, 0, stream>>>(x, xb, c0, c1, c2, wbt);
    k_gemm<<<dim3((Mb / BM) * (Nf / BN)), dim3(512), LDS_BYTES, stream>>>(
        xb, wbt, bias, out, Mb, Nf, Kf);
}